// Round 4
// baseline (12.441 us; speedup 1.0000x reference)
//
#include <hip/hip_runtime.h>

// PARAFAC forward: out[a*200+b] = sum_k F3[a,k]*F4[b,k]*F0[i0,k]*F1[i1,k]*F2[i2,k]
// K=256, dA=dB=200 -> 40,000 fp32 outputs, ~20 MFLOP. Launch/latency-bound.
//
// Round 4: one 16-lane group per (a, 8 consecutive b).
//   - s[k] = F0*F1*F2*F3[a] computed ONCE per group (amortized over 8 outputs)
//   - per b: 4x float4 F4 loads + 16 FMA + 4-step __shfl_xor reduce
//   - lane 0 stores two float4 (8 consecutive outputs, aligned)
// Grid: 200 a * 25 chunks = 5000 groups -> 313 blocks x 256 thr (tail-guarded).

#define KDIM 256
#define DA 200
#define DB 200
#define BPG 8   // b's per group

__global__ __launch_bounds__(256) void parafac_kernel(
    const float* __restrict__ F0, const float* __restrict__ F1,
    const float* __restrict__ F2, const float* __restrict__ F3,
    const float* __restrict__ F4, const int* __restrict__ idx,
    float* __restrict__ out)
{
    const int tid = threadIdx.x;
    const int gg  = blockIdx.x * 16 + (tid >> 4);  // group id, 0..4999
    if (gg >= DA * (DB / BPG)) return;
    const int q   = tid & 15;                      // lane within group

    const int a     = gg / (DB / BPG);     // 0..199
    const int chunk = gg - a * (DB / BPG); // 0..24
    const int b0    = chunk * BPG;         // first of 8 consecutive b

    const int i0 = idx[0];
    const int i1 = idx[1];
    const int i2 = idx[2];

    const int kb = q * 16;            // this lane's k-slice: 16 floats

    const float4* P0 = (const float4*)(F0 + (size_t)i0 * KDIM + kb);
    const float4* P1 = (const float4*)(F1 + (size_t)i1 * KDIM + kb);
    const float4* P2 = (const float4*)(F2 + (size_t)i2 * KDIM + kb);
    const float4* P3 = (const float4*)(F3 + (size_t)a  * KDIM + kb);

    // s = F0*F1*F2*F3[a] on this lane's 16-element k-slice (once per group)
    float4 s[4];
    #pragma unroll
    for (int j = 0; j < 4; ++j) {
        const float4 x0 = P0[j];
        const float4 x1 = P1[j];
        const float4 x2 = P2[j];
        const float4 x3 = P3[j];
        s[j].x = x0.x * x1.x * x2.x * x3.x;
        s[j].y = x0.y * x1.y * x2.y * x3.y;
        s[j].z = x0.z * x1.z * x2.z * x3.z;
        s[j].w = x0.w * x1.w * x2.w * x3.w;
    }

    // 8 dot-products against F4 rows b0..b0+7 (independent chains -> ILP)
    float acc[BPG];
    #pragma unroll
    for (int jb = 0; jb < BPG; ++jb) {
        const float4* P4 = (const float4*)(F4 + (size_t)(b0 + jb) * KDIM + kb);
        float a0 = 0.f, a1 = 0.f, a2 = 0.f, a3 = 0.f;
        #pragma unroll
        for (int j = 0; j < 4; ++j) {
            const float4 v = P4[j];
            a0 = fmaf(v.x, s[j].x, a0);
            a1 = fmaf(v.y, s[j].y, a1);
            a2 = fmaf(v.z, s[j].z, a2);
            a3 = fmaf(v.w, s[j].w, a3);
        }
        acc[jb] = (a0 + a1) + (a2 + a3);
    }

    // reduce each acc over the 16 lanes of the group
    #pragma unroll
    for (int jb = 0; jb < BPG; ++jb) {
        #pragma unroll
        for (int off = 1; off < 16; off <<= 1)
            acc[jb] += __shfl_xor(acc[jb], off, 64);
    }

    if (q == 0) {
        float4 r0 = make_float4(acc[0], acc[1], acc[2], acc[3]);
        float4 r1 = make_float4(acc[4], acc[5], acc[6], acc[7]);
        float* dst = out + (size_t)a * DB + b0;   // 200a+8c: 16B-aligned
        *(float4*)(dst)     = r0;
        *(float4*)(dst + 4) = r1;
    }
}

extern "C" void kernel_launch(void* const* d_in, const int* in_sizes, int n_in,
                              void* d_out, int out_size, void* d_ws, size_t ws_size,
                              hipStream_t stream) {
    const float* F0  = (const float*)d_in[0];
    const float* F1  = (const float*)d_in[1];
    const float* F2  = (const float*)d_in[2];
    const float* F3  = (const float*)d_in[3];
    const float* F4  = (const float*)d_in[4];
    const int*   idx = (const int*)d_in[5];
    float* out = (float*)d_out;

    const int groups = DA * (DB / BPG);          // 5000
    const int blocks = (groups + 15) / 16;       // 313 (tail-guarded)
    parafac_kernel<<<dim3(blocks), dim3(256), 0, stream>>>(F0, F1, F2, F3, F4, idx, out);
}